// Round 8
// baseline (241.848 us; speedup 1.0000x reference)
//
#include <hip/hip_runtime.h>
#include <math.h>

#define B_ 4
#define N_ 2048
#define C_ 768
#define H_ 12
#define D_ 64
// softmax exp(s/8) computed as exp2(s * 0.125*log2(e)); folded into Q pre-scale
#define QKSCALE_ 0.18033688011112042f

typedef unsigned short u16;
typedef unsigned int u32;
typedef short s16x8 __attribute__((ext_vector_type(8)));
typedef float f32x4 __attribute__((ext_vector_type(4)));
typedef u32 u32x2 __attribute__((ext_vector_type(2)));

__device__ __forceinline__ u16 f2bf(float f) {
    union { float f; u32 u; } v; v.f = f;
    u32 r = (v.u + 0x7fffu + ((v.u >> 16) & 1u)) >> 16;
    return (u16)r;
}

// pack two f32 -> bf16x2 (lo=a, hi=b)
__device__ __forceinline__ u32 pkbf(float a, float b) {
    union { float f; u32 u; } ua, ub; ua.f = a; ub.f = b;
    u32 ra = ua.u + 0x7fffu + ((ua.u >> 16) & 1u);
    u32 rb = ub.u + 0x7fffu + ((ub.u >> 16) & 1u);
    return __builtin_amdgcn_perm(rb, ra, 0x07060302u);
}

// async global->LDS, 16B per lane; LDS dest = wave-uniform base + lane*16
__device__ __forceinline__ void gl_lds16(const u16* g, u16* l) {
    __builtin_amdgcn_global_load_lds(
        (__attribute__((address_space(1))) void*)g,
        (__attribute__((address_space(3))) void*)l, 16, 0, 0);
}

// fused fp32 -> bf16 conversion of x, w_qkv, w_proj in one launch
#define NX4_  (B_ * N_ * C_ / 4)
#define NWQ4_ (3 * C_ * C_ / 4)
#define NWP4_ (C_ * C_ / 4)
__global__ __launch_bounds__(256) void cvt_all(const float4* __restrict__ x,
                                               const float4* __restrict__ wq,
                                               const float4* __restrict__ wp,
                                               ushort4* __restrict__ xb,
                                               ushort4* __restrict__ wqb,
                                               ushort4* __restrict__ wpb)
{
    const int tot = NX4_ + NWQ4_ + NWP4_;
    int i = blockIdx.x * blockDim.x + threadIdx.x;
    const int stride = gridDim.x * blockDim.x;
    for (; i < tot; i += stride) {
        const float4* s; ushort4* d; int j;
        if (i < NX4_)              { s = x;  d = xb;  j = i; }
        else if (i < NX4_ + NWQ4_) { s = wq; d = wqb; j = i - NX4_; }
        else                       { s = wp; d = wpb; j = i - NX4_ - NWQ4_; }
        float4 v = s[j];
        ushort4 o;
        o.x = f2bf(v.x); o.y = f2bf(v.y); o.z = f2bf(v.z); o.w = f2bf(v.w);
        d[j] = o;
    }
}

// C(M,N) = A(M,K) * B(N,K)^T [+bias]. BMx128 tile, BK=32, double-buffered
// async staging via global_load_lds(16B). LDS unpadded [rows][32] with XOR
// chunk swizzle: LDS chunk-pos p of row r holds global chunk p ^ ((r>>1)&3).
// BM=256: 32 MFMA per barrier amortizes the vmcnt-drain-at-barrier stall
// (the compiler drains ALL outstanding loads at every barrier, so deeper
// buffering can't help — only more compute per barrier can).
template<int BM, int WPEU, bool OUT_BF16, bool BIAS, bool QSCALE>
__global__ __launch_bounds__(256, WPEU) void gemm_mfma(const u16* __restrict__ A,
                                                       const u16* __restrict__ Bm,
                                                       const float* __restrict__ bias,
                                                       void* __restrict__ Cout,
                                                       int M, int N, int K)
{
    constexpr int MF = BM / 32;          // m-frags per wave (256->8,128->4,64->2)
    constexpr int ACALLS = BM / 64;      // 16-row gl_lds calls per wave for A
    constexpr int ASZ = BM * 32, BSZ = 128 * 32;
    __shared__ __align__(16) u16 As[2 * ASZ];
    __shared__ __align__(16) u16 Bs[2 * BSZ];
    const int tid  = threadIdx.x;
    const int wv   = tid >> 6;
    const int lane = tid & 63;
    const int lr   = lane & 15;
    const int lq   = lane >> 4;
    const int wm   = (wv >> 1) * (BM / 2);
    const int wn   = (wv & 1) * 64;
    const int row0 = blockIdx.y * BM, col0 = blockIdx.x * 128;

    f32x4 acc[MF][4];
    #pragma unroll
    for (int i = 0; i < MF; i++)
        #pragma unroll
        for (int j = 0; j < 4; j++) { f32x4 z = {0.f,0.f,0.f,0.f}; acc[i][j] = z; }

    // staging: one gl_lds16 call per wave stages 16 rows (64 lanes x 16B)
    const int srow   = lane >> 2;                                   // 0..15
    const int schunk = (((lane & 3) ^ ((lane >> 3) & 3)) * 8);      // swizzled

    const int arow_base = (BM / 4) * wv;
    const u16* gA0 = A + (size_t)(row0 + arow_base + srow) * K + schunk;
    const u16* gB0 = Bm + (size_t)(col0 + 32 * wv + srow) * K + schunk;
    const u16* gB1 = gB0 + (size_t)16 * K;
    const int aoff0 = arow_base * 32;
    const int boff0 = (32 * wv) * 32, boff1 = boff0 + 16 * 32;

    const int ppos = (lq ^ ((lr >> 1) & 3)) * 8;   // swizzled frag chunk
    const int nIter = K / 32;

    // prologue: issue tile 0 into buffer 0
    #pragma unroll
    for (int c = 0; c < ACALLS; c++)
        gl_lds16(gA0 + (size_t)(16 * c) * K, As + aoff0 + c * 16 * 32);
    gl_lds16(gB0, Bs + boff0);
    gl_lds16(gB1, Bs + boff1);

    for (int t = 0; t < nIter; t++) {
        const int cur = t & 1;
        __syncthreads();   // vmcnt drain -> buf[cur] ready; buf[cur^1] free
        if (t + 1 < nIter) {
            const int k1 = (t + 1) * 32;
            const int nb = cur ^ 1;
            #pragma unroll
            for (int c = 0; c < ACALLS; c++)
                gl_lds16(gA0 + (size_t)(16 * c) * K + k1,
                         As + nb * ASZ + aoff0 + c * 16 * 32);
            gl_lds16(gB0 + k1, Bs + nb * BSZ + boff0);
            gl_lds16(gB1 + k1, Bs + nb * BSZ + boff1);
        }
        const u16* __restrict__ Ac = As + cur * ASZ;
        const u16* __restrict__ Bc = Bs + cur * BSZ;
        s16x8 af[MF], bfr[4];
        #pragma unroll
        for (int i = 0; i < MF; i++)
            af[i] = *(const s16x8*)&Ac[(wm + 16*i + lr) * 32 + ppos];
        #pragma unroll
        for (int j = 0; j < 4; j++)
            bfr[j] = *(const s16x8*)&Bc[(wn + 16*j + lr) * 32 + ppos];
        #pragma unroll
        for (int i = 0; i < MF; i++)
            #pragma unroll
            for (int j = 0; j < 4; j++)
                acc[i][j] = __builtin_amdgcn_mfma_f32_16x16x32_bf16(af[i], bfr[j], acc[i][j], 0, 0, 0);
    }

    #pragma unroll
    for (int i = 0; i < MF; i++) {
        #pragma unroll
        for (int j = 0; j < 4; j++) {
            const int col = col0 + wn + 16*j + lr;
            float bv = BIAS ? bias[col] : 0.f;
            #pragma unroll
            for (int r = 0; r < 4; r++) {
                const int row = row0 + wm + 16*i + lq*4 + r;
                float v = acc[i][j][r] + bv;
                if (QSCALE && col < C_) v *= QKSCALE_;
                if (OUT_BF16) ((u16*)Cout)[(size_t)row * N + col] = f2bf(v);
                else          ((float*)Cout)[(size_t)row * N + col] = v;
            }
        }
    }
}

// MFMA flash attention, static softmax, register-prefetch pipelined staging.
// Grid (N/128, B*H), 4 waves; wave wv owns q-rows [32wv,32wv+32).
// Ks/Ps: unpadded 64-u16 rows (row step == 0 banks) with 16B-chunk XOR
// swizzle chunk' = chunk ^ (row&7): frag b128 reads tile all 32 banks 2x
// (free), killing the 8-way conflicts of the padded-144B layout.
__global__ __launch_bounds__(256, 4) void attn_mfma(const u16* __restrict__ qkv,
                                                    u16* __restrict__ attout)
{
    __shared__ __align__(16) u16 Ks[64 * 64];   // [key][chunk^(key&7)]
    __shared__ __align__(16) u16 Vt[64][72];    // [d][key], 8-col blocks rotated by d>>3
    __shared__ __align__(16) u16 Ps[128 * 64];  // [q-row][chunk^(row&7)], wave-private

    const int tid  = threadIdx.x;
    const int wv   = tid >> 6;
    const int lane = tid & 63;
    const int lr   = lane & 15;
    const int lq   = lane >> 4;
    const int n0   = blockIdx.x * 128;
    const int bh   = blockIdx.y, b = bh / H_, h = bh % H_;
    const size_t rs = 3 * C_;

    const u16* Qg = qkv + ((size_t)b * N_ + n0) * rs + h * D_;
    const u16* Kg = qkv + ((size_t)b * N_) * rs + C_ + h * D_;
    const u16* Vg = Kg + C_;

    // Q fragments (same lane layout for A- and B-operand roles)
    s16x8 qf[2][2];
    #pragma unroll
    for (int iq = 0; iq < 2; iq++)
        #pragma unroll
        for (int kk = 0; kk < 2; kk++)
            qf[iq][kk] = *(const s16x8*)(Qg + (size_t)(32*wv + 16*iq + lr) * rs + kk*32 + lq*8);

    f32x4 oacc[2][4];
    float li[2] = {0.f, 0.f};
    #pragma unroll
    for (int i = 0; i < 2; i++)
        #pragma unroll
        for (int j = 0; j < 4; j++) { f32x4 z = {0.f,0.f,0.f,0.f}; oacc[i][j] = z; }

    // staging assignments
    const int skey = tid >> 2;                       // K: 1 key, 16 d per thread
    const int sc0  = (tid & 3) * 2;                  // first of two 16B chunks
    const int scA  = (sc0     ^ (skey & 7)) * 8;     // swizzled u16 offsets
    const int scB  = ((sc0+1) ^ (skey & 7)) * 8;
    const int vc = tid & 7, vp = tid >> 3;           // V: 2 keys, 8 d
    const int vkey0 = 2 * vp, vd0 = vc * 8;
    const int vcol0 = (vkey0 + 8 * vc) & 63;

    // prologue: prefetch tile 0 into registers
    s16x8 kr0, kr1, vr0, vr1;
    {
        const u16* kp = Kg + (size_t)skey * rs + sc0 * 8;
        kr0 = *(const s16x8*)kp; kr1 = *(const s16x8*)(kp + 8);
        const u16* vp2 = Vg + (size_t)vkey0 * rs + vd0;
        vr0 = *(const s16x8*)vp2; vr1 = *(const s16x8*)(vp2 + rs);
    }

    for (int t = 0; t < N_ / 64; t++) {
        __syncthreads();   // previous tile's LDS reads complete
        // store prefetched regs -> LDS (chunk-swizzled)
        *(s16x8*)&Ks[skey * 64 + scA] = kr0;
        *(s16x8*)&Ks[skey * 64 + scB] = kr1;
        #pragma unroll
        for (int u = 0; u < 8; u++) {
            u32 pk = (u32)(u16)vr0[u] | ((u32)(u16)vr1[u] << 16);
            *(u32*)&Vt[vd0 + u][vcol0] = pk;
        }
        __syncthreads();
        // issue next tile's global loads (land during this tile's compute)
        if (t + 1 < N_ / 64) {
            const u16* kp = Kg + (size_t)((t+1)*64 + skey) * rs + sc0 * 8;
            kr0 = *(const s16x8*)kp; kr1 = *(const s16x8*)(kp + 8);
            const u16* vp2 = Vg + (size_t)((t+1)*64 + vkey0) * rs + vd0;
            vr0 = *(const s16x8*)vp2; vr1 = *(const s16x8*)(vp2 + rs);
        }

        // S^T = K Q^T : A=K frags, B=Q frags. st[jk][iq]; C-layout:
        // col=lr=q-row, row=lq*4+r=key -> 4 consecutive keys per lane.
        f32x4 st[4][2];
        #pragma unroll
        for (int jk = 0; jk < 4; jk++)
            #pragma unroll
            for (int iq = 0; iq < 2; iq++) { f32x4 z = {0.f,0.f,0.f,0.f}; st[jk][iq] = z; }
        #pragma unroll
        for (int kk = 0; kk < 2; kk++) {
            s16x8 kf[4];
            #pragma unroll
            for (int jk = 0; jk < 4; jk++)
                kf[jk] = *(const s16x8*)&Ks[(16*jk + lr) * 64 + ((4*kk + lq) ^ (lr & 7)) * 8];
            #pragma unroll
            for (int jk = 0; jk < 4; jk++) {
                st[jk][0] = __builtin_amdgcn_mfma_f32_16x16x32_bf16(kf[jk], qf[0][kk], st[jk][0], 0, 0, 0);
                st[jk][1] = __builtin_amdgcn_mfma_f32_16x16x32_bf16(kf[jk], qf[1][kk], st[jk][1], 0, 0, 0);
            }
        }

        // p = exp2(s); deferred row sums; packed b64 P-writes (chunk-swizzled)
        #pragma unroll
        for (int jk = 0; jk < 4; jk++)
            #pragma unroll
            for (int iq = 0; iq < 2; iq++) {
                const float p0 = __builtin_amdgcn_exp2f(st[jk][iq][0]);
                const float p1 = __builtin_amdgcn_exp2f(st[jk][iq][1]);
                const float p2 = __builtin_amdgcn_exp2f(st[jk][iq][2]);
                const float p3 = __builtin_amdgcn_exp2f(st[jk][iq][3]);
                li[iq] += (p0 + p1) + (p2 + p3);
                u32x2 w;
                w.x = pkbf(p0, p1);
                w.y = pkbf(p2, p3);
                const int prow = 32*wv + 16*iq + lr;
                const int pch  = ((2*jk + (lq >> 1)) ^ (lr & 7)) * 8 + (lq & 1) * 4;
                *(u32x2*)&Ps[prow * 64 + pch] = w;
            }
        // no barrier: wave reads only its own Ps rows

        // O += P V : A=P, B=V^T (rotated Vt)
        #pragma unroll
        for (int kk = 0; kk < 2; kk++) {
            s16x8 ap0 = *(const s16x8*)&Ps[(32*wv      + lr) * 64 + ((4*kk + lq) ^ (lr & 7)) * 8];
            s16x8 ap1 = *(const s16x8*)&Ps[(32*wv + 16 + lr) * 64 + ((4*kk + lq) ^ (lr & 7)) * 8];
            #pragma unroll
            for (int j2 = 0; j2 < 4; j2++) {
                const int pb = ((kk*4 + lq) + 2*j2 + (lr >> 3)) & 7;
                s16x8 bv = *(const s16x8*)&Vt[16*j2 + lr][pb * 8];
                oacc[0][j2] = __builtin_amdgcn_mfma_f32_16x16x32_bf16(ap0, bv, oacc[0][j2], 0, 0, 0);
                oacc[1][j2] = __builtin_amdgcn_mfma_f32_16x16x32_bf16(ap1, bv, oacc[1][j2], 0, 0, 0);
            }
        }
    }

    // epilogue: finish li (sum over lq groups), redistribute to oacc rows, store
    #pragma unroll
    for (int iq = 0; iq < 2; iq++) {
        li[iq] += __shfl_xor(li[iq], 16);
        li[iq] += __shfl_xor(li[iq], 32);
    }
    #pragma unroll
    for (int iq = 0; iq < 2; iq++) {
        #pragma unroll
        for (int r = 0; r < 4; r++) {
            const float inv = 1.f / __shfl(li[iq], 4*lq + r);   // li for qrow 16iq+4lq+r
            const int row = n0 + 32*wv + 16*iq + 4*lq + r;
            #pragma unroll
            for (int j2 = 0; j2 < 4; j2++)
                attout[((size_t)(b * N_ + row)) * C_ + h * D_ + 16*j2 + lr] =
                    f2bf(oacc[iq][j2][r] * inv);
        }
    }
}

extern "C" void kernel_launch(void* const* d_in, const int* in_sizes, int n_in,
                              void* d_out, int out_size, void* d_ws, size_t ws_size,
                              hipStream_t stream) {
    const float* x      = (const float*)d_in[0];   // (4,2048,768)
    const float* w_qkv  = (const float*)d_in[1];   // (2304,768)
    const float* w_proj = (const float*)d_in[2];   // (768,768)
    const float* b_proj = (const float*)d_in[3];   // (768,)
    float* out = (float*)d_out;

    const int NX   = B_ * N_ * C_;
    const int NWQ  = 3 * C_ * C_;
    const int NWP  = C_ * C_;
    const int NQKV = B_ * N_ * 3 * C_;

    u16* xb   = (u16*)d_ws;
    u16* wqb  = xb + NX;
    u16* wpb  = wqb + NWQ;
    u16* qkvb = wpb + NWP;
    u16* attb = qkvb + NQKV;

    dim3 blk(256);

    // all three fp32->bf16 conversions in one launch
    cvt_all<<<768, blk, 0, stream>>>((const float4*)x, (const float4*)w_qkv,
                                     (const float4*)w_proj,
                                     (ushort4*)xb, (ushort4*)wqb, (ushort4*)wpb);

    const int M = B_ * N_;   // 8192
    // qkv = x @ w_qkv^T (bf16 out; Q block pre-scaled by 0.125*log2e)
    // BM=256: 32 MFMA per barrier to amortize the per-barrier vmcnt drain
    gemm_mfma<256, 2, true, false, true><<<dim3((3*C_)/128, M/256), blk, 0, stream>>>(
        xb, wqb, nullptr, qkvb, M, 3*C_, C_);

    // flash attention (bf16 in/out), static softmax via exp2
    attn_mfma<<<dim3(N_/128, B_ * H_), blk, 0, stream>>>(qkvb, attb);

    // out = attout @ w_proj^T + b_proj (f32 out), 64-row tile -> 768 blocks
    gemm_mfma<64, 4, false, true, false><<<dim3(C_/128, M/64), blk, 0, stream>>>(
        attb, wpb, b_proj, out, M, C_, C_);
}

// Round 9
// 218.725 us; speedup vs baseline: 1.1057x; 1.1057x over previous
//
#include <hip/hip_runtime.h>
#include <math.h>

#define B_ 4
#define N_ 2048
#define C_ 768
#define H_ 12
#define D_ 64
// softmax exp(s/8) computed as exp2(s * 0.125*log2(e)); folded into Q pre-scale
#define QKSCALE_ 0.18033688011112042f

typedef unsigned short u16;
typedef unsigned int u32;
typedef short s16x8 __attribute__((ext_vector_type(8)));
typedef float f32x4 __attribute__((ext_vector_type(4)));
typedef u32 u32x2 __attribute__((ext_vector_type(2)));

__device__ __forceinline__ u16 f2bf(float f) {
    union { float f; u32 u; } v; v.f = f;
    u32 r = (v.u + 0x7fffu + ((v.u >> 16) & 1u)) >> 16;
    return (u16)r;
}

// pack two f32 -> bf16x2 (lo=a, hi=b)
__device__ __forceinline__ u32 pkbf(float a, float b) {
    union { float f; u32 u; } ua, ub; ua.f = a; ub.f = b;
    u32 ra = ua.u + 0x7fffu + ((ua.u >> 16) & 1u);
    u32 rb = ub.u + 0x7fffu + ((ub.u >> 16) & 1u);
    return __builtin_amdgcn_perm(rb, ra, 0x07060302u);
}

// async global->LDS, 16B per lane; LDS dest = wave-uniform base + lane*16
__device__ __forceinline__ void gl_lds16(const u16* g, u16* l) {
    __builtin_amdgcn_global_load_lds(
        (__attribute__((address_space(1))) void*)g,
        (__attribute__((address_space(3))) void*)l, 16, 0, 0);
}

// fused fp32 -> bf16 conversion of x, w_qkv, w_proj in one launch
#define NX4_  (B_ * N_ * C_ / 4)
#define NWQ4_ (3 * C_ * C_ / 4)
#define NWP4_ (C_ * C_ / 4)
__global__ __launch_bounds__(256) void cvt_all(const float4* __restrict__ x,
                                               const float4* __restrict__ wq,
                                               const float4* __restrict__ wp,
                                               ushort4* __restrict__ xb,
                                               ushort4* __restrict__ wqb,
                                               ushort4* __restrict__ wpb)
{
    const int tot = NX4_ + NWQ4_ + NWP4_;
    int i = blockIdx.x * blockDim.x + threadIdx.x;
    const int stride = gridDim.x * blockDim.x;
    for (; i < tot; i += stride) {
        const float4* s; ushort4* d; int j;
        if (i < NX4_)              { s = x;  d = xb;  j = i; }
        else if (i < NX4_ + NWQ4_) { s = wq; d = wqb; j = i - NX4_; }
        else                       { s = wp; d = wpb; j = i - NX4_ - NWQ4_; }
        float4 v = s[j];
        ushort4 o;
        o.x = f2bf(v.x); o.y = f2bf(v.y); o.z = f2bf(v.z); o.w = f2bf(v.w);
        d[j] = o;
    }
}

// C(M,N) = A(M,K) * B(N,K)^T [+bias]. BMx128 tile, BK=64 (2 MFMA K-steps per
// barrier — per R7/R8: only more MFMA per barrier amortizes the structural
// vmcnt-drain at __syncthreads), double-buffered global_load_lds staging.
// LDS rows of 64 u16 (128B) with 16B-chunk XOR swizzle chunk' = chunk^(row&7):
// staging stays lane-contiguous, frag b128 reads tile the 32 banks evenly.
template<int BM, int WPEU, bool OUT_BF16, bool BIAS, bool QSCALE>
__global__ __launch_bounds__(256, WPEU) void gemm_mfma(const u16* __restrict__ A,
                                                       const u16* __restrict__ Bm,
                                                       const float* __restrict__ bias,
                                                       void* __restrict__ Cout,
                                                       int M, int N, int K)
{
    constexpr int MF  = BM / 32;           // m-frags per wave
    constexpr int AC  = BM / 32;           // A gl_lds calls per wave (8 rows each)
    constexpr int ASZ = BM * 64, BSZ = 128 * 64;
    __shared__ __align__(16) u16 As[2 * ASZ];
    __shared__ __align__(16) u16 Bs[2 * BSZ];
    const int tid  = threadIdx.x;
    const int wv   = tid >> 6;
    const int lane = tid & 63;
    const int lr   = lane & 15;
    const int lq   = lane >> 4;
    const int wm   = (wv >> 1) * (BM / 2);
    const int wn   = (wv & 1) * 64;
    const int row0 = blockIdx.y * BM, col0 = blockIdx.x * 128;

    f32x4 acc[MF][4];
    #pragma unroll
    for (int i = 0; i < MF; i++)
        #pragma unroll
        for (int j = 0; j < 4; j++) { f32x4 z = {0.f,0.f,0.f,0.f}; acc[i][j] = z; }

    // staging lane map: 8 rows x 8 chunks per call; LDS slot (srow,spos) holds
    // global chunk spos^srow  ->  read of global chunk f at row R is at
    // pos f^(R&7).
    const int srow   = lane >> 3;                    // 0..7
    const int schunk = ((lane & 7) ^ srow) * 8;      // swizzled global chunk (u16)

    const int arow_base = (BM / 4) * wv;             // wave's A rows
    const u16* gA = A + (size_t)(row0 + arow_base + srow) * K + schunk;
    const u16* gB = Bm + (size_t)(col0 + 32 * wv + srow) * K + schunk;
    const int aoff = arow_base * 64;
    const int boff = (32 * wv) * 64;

    const int nIter = K / 64;

    // prologue: issue tile 0 into buffer 0
    #pragma unroll
    for (int c = 0; c < AC; c++)
        gl_lds16(gA + (size_t)(8 * c) * K, As + aoff + c * 8 * 64);
    #pragma unroll
    for (int c = 0; c < 4; c++)
        gl_lds16(gB + (size_t)(8 * c) * K, Bs + boff + c * 8 * 64);

    for (int t = 0; t < nIter; t++) {
        const int cur = t & 1;
        __syncthreads();   // buf[cur] staged; buf[cur^1] free
        if (t + 1 < nIter) {
            const int k1 = (t + 1) * 64;
            const int nb = cur ^ 1;
            #pragma unroll
            for (int c = 0; c < AC; c++)
                gl_lds16(gA + (size_t)(8 * c) * K + k1, As + nb * ASZ + aoff + c * 8 * 64);
            #pragma unroll
            for (int c = 0; c < 4; c++)
                gl_lds16(gB + (size_t)(8 * c) * K + k1, Bs + nb * BSZ + boff + c * 8 * 64);
        }
        const u16* __restrict__ Ac = As + cur * ASZ;
        const u16* __restrict__ Bc = Bs + cur * BSZ;
        #pragma unroll
        for (int kk = 0; kk < 2; kk++) {
            const int fo = ((4 * kk + lq) ^ (lr & 7)) * 8;   // swizzled frag pos
            s16x8 af[MF], bfr[4];
            #pragma unroll
            for (int i = 0; i < MF; i++)
                af[i] = *(const s16x8*)&Ac[(wm + 16*i + lr) * 64 + fo];
            #pragma unroll
            for (int j = 0; j < 4; j++)
                bfr[j] = *(const s16x8*)&Bc[(wn + 16*j + lr) * 64 + fo];
            #pragma unroll
            for (int i = 0; i < MF; i++)
                #pragma unroll
                for (int j = 0; j < 4; j++)
                    acc[i][j] = __builtin_amdgcn_mfma_f32_16x16x32_bf16(af[i], bfr[j], acc[i][j], 0, 0, 0);
        }
    }

    #pragma unroll
    for (int i = 0; i < MF; i++) {
        #pragma unroll
        for (int j = 0; j < 4; j++) {
            const int col = col0 + wn + 16*j + lr;
            float bv = BIAS ? bias[col] : 0.f;
            #pragma unroll
            for (int r = 0; r < 4; r++) {
                const int row = row0 + wm + 16*i + lq*4 + r;
                float v = acc[i][j][r] + bv;
                if (QSCALE && col < C_) v *= QKSCALE_;
                if (OUT_BF16) ((u16*)Cout)[(size_t)row * N + col] = f2bf(v);
                else          ((float*)Cout)[(size_t)row * N + col] = v;
            }
        }
    }
}

// MFMA flash attention, static softmax, single-barrier double-buffered K/V
// staging. Grid (N/128, B*H), 4 waves; wave wv owns q-rows [32wv,32wv+32).
// Per tile t: barrier -> store reg-prefetched tile t+1 into buf[nxt] ->
// issue global loads for t+2 -> compute tile t from buf[cur]. One barrier
// per tile (was two). lb(256,3): R8 showed lb4 squeezes VGPR and spills the
// prefetch pipeline to scratch (WRITE_SIZE +8MB) — don't.
__global__ __launch_bounds__(256, 3) void attn_mfma(const u16* __restrict__ qkv,
                                                    u16* __restrict__ attout)
{
    __shared__ __align__(16) u16 Ks[2][64 * 64];   // [key][chunk^(key&7)]
    __shared__ __align__(16) u16 Vt[2][64][72];    // [d][key], 8-col blocks rotated
    __shared__ __align__(16) u16 Ps[128 * 64];     // [q-row][chunk^(row&7)], wave-private

    const int tid  = threadIdx.x;
    const int wv   = tid >> 6;
    const int lane = tid & 63;
    const int lr   = lane & 15;
    const int lq   = lane >> 4;
    const int n0   = blockIdx.x * 128;
    const int bh   = blockIdx.y, b = bh / H_, h = bh % H_;
    const size_t rs = 3 * C_;

    const u16* Qg = qkv + ((size_t)b * N_ + n0) * rs + h * D_;
    const u16* Kg = qkv + ((size_t)b * N_) * rs + C_ + h * D_;
    const u16* Vg = Kg + C_;

    // Q fragments (same lane layout for A- and B-operand roles)
    s16x8 qf[2][2];
    #pragma unroll
    for (int iq = 0; iq < 2; iq++)
        #pragma unroll
        for (int kk = 0; kk < 2; kk++)
            qf[iq][kk] = *(const s16x8*)(Qg + (size_t)(32*wv + 16*iq + lr) * rs + kk*32 + lq*8);

    f32x4 oacc[2][4];
    float li[2] = {0.f, 0.f};
    #pragma unroll
    for (int i = 0; i < 2; i++)
        #pragma unroll
        for (int j = 0; j < 4; j++) { f32x4 z = {0.f,0.f,0.f,0.f}; oacc[i][j] = z; }

    // staging assignments
    const int skey = tid >> 2;                       // K: 1 key, 16 d per thread
    const int sc0  = (tid & 3) * 2;                  // first of two 16B chunks
    const int scA  = (sc0     ^ (skey & 7)) * 8;     // swizzled u16 offsets
    const int scB  = ((sc0+1) ^ (skey & 7)) * 8;
    const int vc = tid & 7, vp = tid >> 3;           // V: 2 keys, 8 d
    const int vkey0 = 2 * vp, vd0 = vc * 8;
    const int vcol0 = (vkey0 + 8 * vc) & 63;

    // prologue: tile 0 -> regs -> buf0; tile 1 -> regs
    s16x8 kr0, kr1, vr0, vr1;
    {
        const u16* kp = Kg + (size_t)skey * rs + sc0 * 8;
        kr0 = *(const s16x8*)kp; kr1 = *(const s16x8*)(kp + 8);
        const u16* vp2 = Vg + (size_t)vkey0 * rs + vd0;
        vr0 = *(const s16x8*)vp2; vr1 = *(const s16x8*)(vp2 + rs);
    }
    *(s16x8*)&Ks[0][skey * 64 + scA] = kr0;
    *(s16x8*)&Ks[0][skey * 64 + scB] = kr1;
    #pragma unroll
    for (int u = 0; u < 8; u++) {
        u32 pk = (u32)(u16)vr0[u] | ((u32)(u16)vr1[u] << 16);
        *(u32*)&Vt[0][vd0 + u][vcol0] = pk;
    }
    {
        const u16* kp = Kg + (size_t)(64 + skey) * rs + sc0 * 8;
        kr0 = *(const s16x8*)kp; kr1 = *(const s16x8*)(kp + 8);
        const u16* vp2 = Vg + (size_t)(64 + vkey0) * rs + vd0;
        vr0 = *(const s16x8*)vp2; vr1 = *(const s16x8*)(vp2 + rs);
    }

    const int NT = N_ / 64;
    for (int t = 0; t < NT; t++) {
        const int cur = t & 1, nxt = cur ^ 1;
        __syncthreads();   // buf[cur] staged by all waves; buf[nxt] readers done
        if (t + 1 < NT) {
            *(s16x8*)&Ks[nxt][skey * 64 + scA] = kr0;
            *(s16x8*)&Ks[nxt][skey * 64 + scB] = kr1;
            #pragma unroll
            for (int u = 0; u < 8; u++) {
                u32 pk = (u32)(u16)vr0[u] | ((u32)(u16)vr1[u] << 16);
                *(u32*)&Vt[nxt][vd0 + u][vcol0] = pk;
            }
        }
        if (t + 2 < NT) {
            const u16* kp = Kg + (size_t)((t+2)*64 + skey) * rs + sc0 * 8;
            kr0 = *(const s16x8*)kp; kr1 = *(const s16x8*)(kp + 8);
            const u16* vp2 = Vg + (size_t)((t+2)*64 + vkey0) * rs + vd0;
            vr0 = *(const s16x8*)vp2; vr1 = *(const s16x8*)(vp2 + rs);
        }

        // S^T = K Q^T : A=K frags, B=Q frags. C-layout: col=lr=q-row,
        // row=lq*4+r=key -> 4 consecutive keys per lane.
        f32x4 st[4][2];
        #pragma unroll
        for (int jk = 0; jk < 4; jk++)
            #pragma unroll
            for (int iq = 0; iq < 2; iq++) { f32x4 z = {0.f,0.f,0.f,0.f}; st[jk][iq] = z; }
        #pragma unroll
        for (int kk = 0; kk < 2; kk++) {
            s16x8 kf[4];
            #pragma unroll
            for (int jk = 0; jk < 4; jk++)
                kf[jk] = *(const s16x8*)&Ks[cur][(16*jk + lr) * 64 + ((4*kk + lq) ^ (lr & 7)) * 8];
            #pragma unroll
            for (int jk = 0; jk < 4; jk++) {
                st[jk][0] = __builtin_amdgcn_mfma_f32_16x16x32_bf16(kf[jk], qf[0][kk], st[jk][0], 0, 0, 0);
                st[jk][1] = __builtin_amdgcn_mfma_f32_16x16x32_bf16(kf[jk], qf[1][kk], st[jk][1], 0, 0, 0);
            }
        }

        // p = exp2(s); deferred row sums; packed b64 P-writes (chunk-swizzled)
        #pragma unroll
        for (int jk = 0; jk < 4; jk++)
            #pragma unroll
            for (int iq = 0; iq < 2; iq++) {
                const float p0 = __builtin_amdgcn_exp2f(st[jk][iq][0]);
                const float p1 = __builtin_amdgcn_exp2f(st[jk][iq][1]);
                const float p2 = __builtin_amdgcn_exp2f(st[jk][iq][2]);
                const float p3 = __builtin_amdgcn_exp2f(st[jk][iq][3]);
                li[iq] += (p0 + p1) + (p2 + p3);
                u32x2 w;
                w.x = pkbf(p0, p1);
                w.y = pkbf(p2, p3);
                const int prow = 32*wv + 16*iq + lr;
                const int pch  = ((2*jk + (lq >> 1)) ^ (lr & 7)) * 8 + (lq & 1) * 4;
                *(u32x2*)&Ps[prow * 64 + pch] = w;
            }
        // no barrier: wave reads only its own Ps rows

        // O += P V : A=P, B=V^T (rotated Vt)
        #pragma unroll
        for (int kk = 0; kk < 2; kk++) {
            s16x8 ap0 = *(const s16x8*)&Ps[(32*wv      + lr) * 64 + ((4*kk + lq) ^ (lr & 7)) * 8];
            s16x8 ap1 = *(const s16x8*)&Ps[(32*wv + 16 + lr) * 64 + ((4*kk + lq) ^ (lr & 7)) * 8];
            #pragma unroll
            for (int j2 = 0; j2 < 4; j2++) {
                const int pb = ((kk*4 + lq) + 2*j2 + (lr >> 3)) & 7;
                s16x8 bv = *(const s16x8*)&Vt[cur][16*j2 + lr][pb * 8];
                oacc[0][j2] = __builtin_amdgcn_mfma_f32_16x16x32_bf16(ap0, bv, oacc[0][j2], 0, 0, 0);
                oacc[1][j2] = __builtin_amdgcn_mfma_f32_16x16x32_bf16(ap1, bv, oacc[1][j2], 0, 0, 0);
            }
        }
    }

    // epilogue: finish li (sum over lq groups), redistribute to oacc rows, store
    #pragma unroll
    for (int iq = 0; iq < 2; iq++) {
        li[iq] += __shfl_xor(li[iq], 16);
        li[iq] += __shfl_xor(li[iq], 32);
    }
    #pragma unroll
    for (int iq = 0; iq < 2; iq++) {
        #pragma unroll
        for (int r = 0; r < 4; r++) {
            const float inv = 1.f / __shfl(li[iq], 4*lq + r);   // li for qrow 16iq+4lq+r
            const int row = n0 + 32*wv + 16*iq + 4*lq + r;
            #pragma unroll
            for (int j2 = 0; j2 < 4; j2++)
                attout[((size_t)(b * N_ + row)) * C_ + h * D_ + 16*j2 + lr] =
                    f2bf(oacc[iq][j2][r] * inv);
        }
    }
}

extern "C" void kernel_launch(void* const* d_in, const int* in_sizes, int n_in,
                              void* d_out, int out_size, void* d_ws, size_t ws_size,
                              hipStream_t stream) {
    const float* x      = (const float*)d_in[0];   // (4,2048,768)
    const float* w_qkv  = (const float*)d_in[1];   // (2304,768)
    const float* w_proj = (const float*)d_in[2];   // (768,768)
    const float* b_proj = (const float*)d_in[3];   // (768,)
    float* out = (float*)d_out;

    const int NX   = B_ * N_ * C_;
    const int NWQ  = 3 * C_ * C_;
    const int NWP  = C_ * C_;
    const int NQKV = B_ * N_ * 3 * C_;

    u16* xb   = (u16*)d_ws;
    u16* wqb  = xb + NX;
    u16* wpb  = wqb + NWQ;
    u16* qkvb = wpb + NWP;
    u16* attb = qkvb + NQKV;

    dim3 blk(256);

    // all three fp32->bf16 conversions in one launch
    cvt_all<<<768, blk, 0, stream>>>((const float4*)x, (const float4*)w_qkv,
                                     (const float4*)w_proj,
                                     (ushort4*)xb, (ushort4*)wqb, (ushort4*)wpb);

    const int M = B_ * N_;   // 8192
    // qkv = x @ w_qkv^T (bf16 out; Q block pre-scaled by 0.125*log2e)
    gemm_mfma<128, 2, true, false, true><<<dim3((3*C_)/128, M/128), blk, 0, stream>>>(
        xb, wqb, nullptr, qkvb, M, 3*C_, C_);

    // flash attention (bf16 in/out), static softmax via exp2
    attn_mfma<<<dim3(N_/128, B_ * H_), blk, 0, stream>>>(qkvb, attb);

    // out = attout @ w_proj^T + b_proj (f32 out)
    gemm_mfma<64, 3, false, true, false><<<dim3(C_/128, M/64), blk, 0, stream>>>(
        attb, wpb, b_proj, out, M, C_, C_);
}